// Round 1
// baseline (528.282 us; speedup 1.0000x reference)
//
#include <hip/hip_runtime.h>
#include <math.h>

#define AA 48          // A = DIST^2 - 1
#define RR 25          // ROUNDS
#define TT 23          // R - 2 scan steps
#define ND 1176        // A*(A+1)/2
#define NOFF 1128      // ND - A (nondiag count)
#define BPB 4          // batches per block
#define NTHREADS 256

__global__ __launch_bounds__(NTHREADS) void cnn_embed_kernel(
    const int*   __restrict__ x,        // (B, 25, 48) int32 in {0,1}
    const float* __restrict__ emb_diag, // (1, 48)
    const float* __restrict__ emb_nd,   // (1, 1128, 4)
    float*       __restrict__ out,      // (B, 23, 1176)
    int B)
{
    __shared__ uint8_t  xls[BPB * RR * AA];   // staged x bits (4800 B)
    __shared__ uint8_t  xxc[BPB * TT * AA];   // xx codes in {2,3,4} (4416 B)
    __shared__ uint16_t pairs[ND];            // (i | j<<8) per output col (2352 B)
    __shared__ float4   gtab[ND];             // value for prod {12,9,8,6} (18816 B)

    const int tid = threadIdx.x;
    const int b0  = blockIdx.x * BPB;

    // ---- Phase A: per-block tables (identical across blocks; cheap) ----
    for (int p = tid; p < AA; p += NTHREADS) {
        pairs[p] = (uint16_t)(p | (p << 8));
        float s = 1.0f / (1.0f + __expf(-emb_diag[p]));
        gtab[p] = make_float4(0.0f, s, 0.0f, 0.0f);   // diag: prod 9 -> sig_diag
    }
    for (int pp = tid; pp < NOFF; pp += NTHREADS) {
        // row iy of upper-triangular (excl diag): S(iy) = 47*iy - iy*(iy-1)/2
        int iy = (int)((95.0f - sqrtf(9025.0f - 8.0f * (float)pp)) * 0.5f);
        if (iy < 0) iy = 0;
        if (iy > 46) iy = 46;
        while (iy < 46 && (47 * (iy + 1) - ((iy + 1) * iy) / 2) <= pp) ++iy;
        while (iy > 0 && (47 * iy - (iy * (iy - 1)) / 2) > pp) --iy;
        int S  = 47 * iy - (iy * (iy - 1)) / 2;
        int ix = iy + 1 + (pp - S);
        pairs[AA + pp] = (uint16_t)(iy | (ix << 8));
        const float* e = emb_nd + pp * 4;
        float f12 = 1.0f / (1.0f + __expf(-e[0]));
        float f9  = f12 / (1.0f + __expf(-e[1]));
        float f8  = f9  / (1.0f + __expf(-e[2]));
        float f6  = f8  / (1.0f + __expf(-e[3]));
        gtab[AA + pp] = make_float4(f12, f9, f8, f6);
    }

    // ---- Phase B: stage x for BPB batches as packed bytes ----
    {
        int validB = B - b0;
        if (validB > BPB) validB = BPB;
        const int validInts = validB * RR * AA;          // multiple of 4 (1200/batch)
        const int4* xg = (const int4*)(x + (size_t)b0 * RR * AA);
        for (int g = tid; g * 4 < validInts; g += NTHREADS) {
            int4 v = xg[g];
            uint32_t packed = (uint32_t)(v.x & 1) | ((uint32_t)(v.y & 1) << 8) |
                              ((uint32_t)(v.z & 1) << 16) | ((uint32_t)(v.w & 1) << 24);
            *((uint32_t*)&xls[g * 4]) = packed;
        }
    }
    __syncthreads();

    // ---- Phase C: integer recurrence; thread = (bb, j), 192 active ----
    if (tid < BPB * AA) {
        const int bb = tid / AA;
        const int j  = tid - bb * AA;
        if (b0 + bb < B) {
            const uint8_t* xb  = &xls[bb * RR * AA];
            uint8_t*       xxb = &xxc[bb * TT * AA];
            int st = -1, dt = 1;
            for (int t = 0; t < TT; ++t) {
                int a  = xb[t * AA + j];
                int bv = xb[(t + 1) * AA + j];
                int c  = xb[(t + 2) * AA + j];
                int de = a ^ c;                       // data_err
                int me = de ? 0 : (a ^ bv);           // meas_err (only if a==c)
                if (me) dt = -dt;
                st += dt * de;
                st = st < -1 ? -1 : (st > 1 ? 1 : st);
                if (!me) dt = (st == 0) ? dt : -st;   // dt*(1-st^2) - st
                xxb[t * AA + j] = (uint8_t)(st + 3);  // xx in {2,3,4}
            }
        }
    }
    __syncthreads();

    // ---- Phase D: coalesced output writes ----
    for (int bb = 0; bb < BPB; ++bb) {
        const int b = b0 + bb;
        if (b >= B) break;
        const uint8_t* xxb = &xxc[bb * TT * AA];
        float* ob = out + (size_t)b * TT * ND;
        for (int t = 0; t < TT; ++t) {
            const uint8_t* xr = &xxb[t * AA];
            float* orow = ob + t * ND;
            for (int p = tid; p < ND; p += NTHREADS) {
                uint32_t pr = pairs[p];
                int i  = pr & 0xFF;
                int jj = pr >> 8;
                int prod = (int)xr[i] * (int)xr[jj];  // in {4,6,8,9,12,16}
                float4 g = gtab[p];
                float v = 0.0f;
                v = (prod == 6)  ? g.w : v;
                v = (prod == 8)  ? g.z : v;
                v = (prod == 9)  ? g.y : v;
                v = (prod == 12) ? g.x : v;
                v = (prod == 16) ? 1.0f : v;
                orow[p] = v;
            }
        }
    }
}

extern "C" void kernel_launch(void* const* d_in, const int* in_sizes, int n_in,
                              void* d_out, int out_size, void* d_ws, size_t ws_size,
                              hipStream_t stream) {
    const int*   x  = (const int*)d_in[0];
    const float* ed = (const float*)d_in[1];
    const float* en = (const float*)d_in[2];
    float* out = (float*)d_out;
    const int B = in_sizes[0] / (RR * AA);   // 4096
    const int grid = (B + BPB - 1) / BPB;
    hipLaunchKernelGGL(cnn_embed_kernel, dim3(grid), dim3(NTHREADS), 0, stream,
                       x, ed, en, out, B);
}

// Round 2
// 483.681 us; speedup vs baseline: 1.0922x; 1.0922x over previous
//
#include <hip/hip_runtime.h>
#include <math.h>

#define AA 48          // A = DIST^2 - 1
#define RR 25          // ROUNDS
#define TT 23          // R - 2 scan steps
#define ND 1176        // A*(A+1)/2
#define NOFF 1128      // ND - A (nondiag count)
#define BPB 4          // batches per block
#define NT 320         // 5 waves; threads 0..293 own 4 outputs each (294*4 = 1176)
#define NOWN 294

// d_ws layout: float4 gtab[1176] @ 0 (18816 B), uint32 pairs[1176] @ 18816 (4704 B)
#define GTAB_BYTES (ND * 16)

__global__ __launch_bounds__(256) void build_tables_kernel(
    const float* __restrict__ emb_diag,  // (1, 48)
    const float* __restrict__ emb_nd,    // (1, 1128, 4)
    float4* __restrict__ gtab,           // [1176] value for prod {12,9,8,6}
    uint32_t* __restrict__ pairs)        // [1176] i | (j<<8)
{
    int p = blockIdx.x * 256 + threadIdx.x;
    if (p >= ND) return;
    if (p < AA) {
        pairs[p] = (uint32_t)(p | (p << 8));
        float s = 1.0f / (1.0f + __expf(-emb_diag[p]));
        gtab[p] = make_float4(0.0f, s, 0.0f, 0.0f);   // diag: prod 9 -> sig_diag
    } else {
        int pp = p - AA;
        // row iy of strict upper triangle: S(iy) = 47*iy - iy*(iy-1)/2
        int iy = (int)((95.0f - sqrtf(9025.0f - 8.0f * (float)pp)) * 0.5f);
        if (iy < 0) iy = 0;
        if (iy > 46) iy = 46;
        while (iy < 46 && (47 * (iy + 1) - ((iy + 1) * iy) / 2) <= pp) ++iy;
        while (iy > 0 && (47 * iy - (iy * (iy - 1)) / 2) > pp) --iy;
        int S  = 47 * iy - (iy * (iy - 1)) / 2;
        int ix = iy + 1 + (pp - S);
        pairs[p] = (uint32_t)(iy | (ix << 8));
        const float* e = emb_nd + pp * 4;
        float f12 = 1.0f / (1.0f + __expf(-e[0]));
        float f9  = f12 / (1.0f + __expf(-e[1]));
        float f8  = f9  / (1.0f + __expf(-e[2]));
        float f6  = f8  / (1.0f + __expf(-e[3]));
        gtab[p] = make_float4(f12, f9, f8, f6);
    }
}

__global__ __launch_bounds__(NT) void cnn_embed_kernel(
    const int*      __restrict__ x,      // (B, 25, 48) int32 in {0,1}
    const float4*   __restrict__ gtab,   // [1176]
    const uint32_t* __restrict__ pairs,  // [1176]
    float*          __restrict__ out,    // (B, 23, 1176)
    int B)
{
    __shared__ uint8_t xls[BPB * RR * AA];   // staged x bits (4800 B)
    __shared__ uint8_t xxc[BPB * TT * AA];   // xx codes in {2,3,4} (4416 B)

    const int tid = threadIdx.x;
    const int b0  = blockIdx.x * BPB;

    // ---- Per-thread table registers: thread owns p = 4*tid .. 4*tid+3 ----
    const bool owner = (tid < NOWN);
    int iidx[4], jidx[4];
    float4 g[4];
    if (owner) {
        uint4 pr = ((const uint4*)pairs)[tid];   // pairs[4*tid .. 4*tid+3]
        iidx[0] = pr.x & 0xFF; jidx[0] = (pr.x >> 8) & 0xFF;
        iidx[1] = pr.y & 0xFF; jidx[1] = (pr.y >> 8) & 0xFF;
        iidx[2] = pr.z & 0xFF; jidx[2] = (pr.z >> 8) & 0xFF;
        iidx[3] = pr.w & 0xFF; jidx[3] = (pr.w >> 8) & 0xFF;
        #pragma unroll
        for (int k = 0; k < 4; ++k) g[k] = gtab[4 * tid + k];
    }

    // ---- Stage x bits as packed bytes ----
    {
        int validB = B - b0;
        if (validB > BPB) validB = BPB;
        const int validInts = validB * RR * AA;          // 1200/batch
        const int4* xg = (const int4*)(x + (size_t)b0 * RR * AA);
        for (int gg = tid; gg * 4 < validInts; gg += NT) {
            int4 v = xg[gg];
            uint32_t packed = (uint32_t)(v.x & 1) | ((uint32_t)(v.y & 1) << 8) |
                              ((uint32_t)(v.z & 1) << 16) | ((uint32_t)(v.w & 1) << 24);
            *((uint32_t*)&xls[gg * 4]) = packed;
        }
    }
    __syncthreads();

    // ---- Integer recurrence; thread = (bb, j), 192 active ----
    if (tid < BPB * AA) {
        const int bb = tid / AA;
        const int j  = tid - bb * AA;
        if (b0 + bb < B) {
            const uint8_t* xb  = &xls[bb * RR * AA];
            uint8_t*       xxb = &xxc[bb * TT * AA];
            int st = -1, dt = 1;
            #pragma unroll
            for (int t = 0; t < TT; ++t) {
                int a  = xb[t * AA + j];
                int bv = xb[(t + 1) * AA + j];
                int c  = xb[(t + 2) * AA + j];
                int de = a ^ c;                       // data_err
                int me = de ? 0 : (a ^ bv);           // meas_err
                if (me) dt = -dt;
                st += dt * de;
                st = st < -1 ? -1 : (st > 1 ? 1 : st);
                if (!me) dt = (st == 0) ? dt : -st;   // dt*(1-st^2) - st
                xxb[t * AA + j] = (uint8_t)(st + 3);  // xx in {2,3,4}
            }
        }
    }
    __syncthreads();

    // ---- Output: thread writes float4 at p=4*tid for every (bb, t) ----
    if (owner) {
        #pragma unroll
        for (int bb = 0; bb < BPB; ++bb) {
            const int b = b0 + bb;
            if (b >= B) break;
            const uint8_t* xxb = &xxc[bb * TT * AA];
            float* ob = out + (size_t)b * TT * ND + tid * 4;
            for (int t = 0; t < TT; ++t) {
                const uint8_t* xr = &xxb[t * AA];
                float4 v;
                float* vf = (float*)&v;
                #pragma unroll
                for (int k = 0; k < 4; ++k) {
                    int prod = (int)xr[iidx[k]] * (int)xr[jidx[k]];  // {4,6,8,9,12,16}
                    float r = 0.0f;
                    r = (prod == 6)  ? g[k].w : r;
                    r = (prod == 8)  ? g[k].z : r;
                    r = (prod == 9)  ? g[k].y : r;
                    r = (prod == 12) ? g[k].x : r;
                    r = (prod == 16) ? 1.0f   : r;
                    vf[k] = r;
                }
                *((float4*)(ob + t * ND)) = v;
            }
        }
    }
}

extern "C" void kernel_launch(void* const* d_in, const int* in_sizes, int n_in,
                              void* d_out, int out_size, void* d_ws, size_t ws_size,
                              hipStream_t stream) {
    const int*   x  = (const int*)d_in[0];
    const float* ed = (const float*)d_in[1];
    const float* en = (const float*)d_in[2];
    float* out = (float*)d_out;
    float4*   gtab  = (float4*)d_ws;
    uint32_t* pairs = (uint32_t*)((char*)d_ws + GTAB_BYTES);
    const int B = in_sizes[0] / (RR * AA);   // 4096

    hipLaunchKernelGGL(build_tables_kernel, dim3((ND + 255) / 256), dim3(256), 0, stream,
                       ed, en, gtab, pairs);
    const int grid = (B + BPB - 1) / BPB;
    hipLaunchKernelGGL(cnn_embed_kernel, dim3(grid), dim3(NT), 0, stream,
                       x, gtab, pairs, out, B);
}